// Round 7
// baseline (297.108 us; speedup 1.0000x reference)
//
#include <hip/hip_runtime.h>

#define POOL 7
#define NROIS 1000
#define NCELLS (NROIS * POOL * POOL)     // 49000 output cells
#define IMG_W 128
#define NCH 1024
#define NXCD 8
#define CG_CH 64                         // channels per group slice (256 B)
#define NGRP (NCH / CG_CH)               // 16 groups
#define PHASES (NGRP / NXCD)             // 2 sequential phases per XCD
#define CELLS_PER_BLK 16                 // 256 thr = 16 cells x 16 lanes x f4
#define NBLK_CELLS ((NCELLS + CELLS_PER_BLK - 1) / CELLS_PER_BLK)  // 3063

typedef float f4 __attribute__((ext_vector_type(4)));

// Channel-sharded ROI bilinear pooling, 16 groups of 64 ch (256 B each).
// bid%8 == XCD id (round-robin dispatch heuristic). XCD k processes group k
// for ALL 49000 cells (phase 0), then group k+8 (phase 1) — phase derived
// from block slot, so dispatch order keeps one 4 MB channel slice (== XCD
// L2 size) resident at a time. Nontemporal stores keep the output stream
// from evicting it. Every image byte fetched from HBM by exactly one XCD
// -> ideal chip-wide FETCH = 64 MB. A/B vs round 4 (G=8: 8 MB slice,
// 512 B segments, no phases): trades segment size for L2 residency.
__global__ __launch_bounds__(256) void roi_pool_kernel(
    const float* __restrict__ img,
    const int* __restrict__ rois,
    float* __restrict__ out)
{
    const unsigned bid   = blockIdx.x;
    const unsigned xcd   = bid & 7u;           // presumed XCD of this block
    const unsigned slot  = bid >> 3;           // per-XCD sequential slot
    const unsigned phase = slot / NBLK_CELLS;  // 0 or 1
    const unsigned cblk  = slot - phase * NBLK_CELLS;
    const unsigned g     = phase * NXCD + xcd; // channel group 0..15

    const unsigned t    = threadIdx.x;         // 0..255
    const unsigned cell = cblk * CELLS_PER_BLK + (t >> 4);  // 16 lanes/cell
    if (cell >= NCELLS) return;
    const unsigned lane = t & 15u;

    const unsigned roi = cell / 49u;
    const unsigned c49 = cell - roi * 49u;
    const unsigned py  = c49 / 7u;
    const unsigned px  = c49 - py * 7u;

    const int4 r = ((const int4*)rois)[roi];   // x, y, w, h
    const int x = r.x, y = r.y, w = r.z, h = r.w;

    // y-axis source coords (match reference op order exactly)
    const float hf = (float)h;
    float fy = ((float)py + 0.5f) * (hf / (float)POOL) - 0.5f;
    fy = fminf(fmaxf(fy, 0.0f), fmaxf(hf - 1.0f, 0.0f));
    const int   iy0 = (int)floorf(fy);
    const int   iy1 = min(iy0 + 1, h - 1);
    const float wy  = fy - (float)iy0;
    const int   y0  = y + iy0;
    const int   y1  = y + iy1;

    // x-axis source coords
    const float wf = (float)w;
    float fx = ((float)px + 0.5f) * (wf / (float)POOL) - 0.5f;
    fx = fminf(fmaxf(fx, 0.0f), fmaxf(wf - 1.0f, 0.0f));
    const int   ix0 = (int)floorf(fx);
    const int   ix1 = min(ix0 + 1, w - 1);
    const float wx  = fx - (float)ix0;
    const int   x0  = x + ix0;
    const int   x1  = x + ix1;

    // channel offset: this group's slice base + lane quad
    const unsigned choff = g * CG_CH + lane * 4u;

    const f4* p00 = (const f4*)(img + ((size_t)y0 * IMG_W + x0) * NCH + choff);
    const f4* p01 = (const f4*)(img + ((size_t)y0 * IMG_W + x1) * NCH + choff);
    const f4* p10 = (const f4*)(img + ((size_t)y1 * IMG_W + x0) * NCH + choff);
    const f4* p11 = (const f4*)(img + ((size_t)y1 * IMG_W + x1) * NCH + choff);
    f4* po = (f4*)(out + (size_t)cell * NCH + choff);

    const f4 a = *p00;
    const f4 b = *p01;
    const f4 c = *p10;
    const f4 d = *p11;

    const float owx = 1.0f - wx;
    const float owy = 1.0f - wy;

    const f4 top = a * owx + b * wx;
    const f4 bot = c * owx + d * wx;
    const f4 res = top * owy + bot * wy;

    __builtin_nontemporal_store(res, po);
}

extern "C" void kernel_launch(void* const* d_in, const int* in_sizes, int n_in,
                              void* d_out, int out_size, void* d_ws, size_t ws_size,
                              hipStream_t stream)
{
    const float* img  = (const float*)d_in[0];
    const int*   rois = (const int*)d_in[1];
    float*       out  = (float*)d_out;

    const int nblocks = NBLK_CELLS * PHASES * NXCD;   // 3063 * 2 * 8 = 49008
    roi_pool_kernel<<<nblocks, 256, 0, stream>>>(img, rois, out);
}